// Round 1
// baseline (75.139 us; speedup 1.0000x reference)
//
#include <hip/hip_runtime.h>

#define NORB  12
#define NFEAT 14
#define NCOL1 144
#define NCOL2 20736
#define BLK   256

// Block-wide double reduction. Valid result on thread 0 only.
__device__ inline double block_reduce_d(double v, double* red, int tid) {
    #pragma unroll
    for (int o = 32; o > 0; o >>= 1) v += __shfl_down(v, o, 64);
    if ((tid & 63) == 0) red[tid >> 6] = v;
    __syncthreads();
    double r = 0.0;
    if (tid == 0) {
        #pragma unroll
        for (int wv = 0; wv < BLK / 64; ++wv) r += red[wv];
    }
    __syncthreads();   // safe to reuse `red` after return
    return r;
}

extern "C" __global__ void __launch_bounds__(BLK)
eloc_main(const float* __restrict__ mfv, const float* __restrict__ h1,
          const float* __restrict__ h2, const int* __restrict__ vn,
          const float* __restrict__ w, double* __restrict__ ep_ws)
{
    const int t   = blockIdx.x;
    const int tid = threadIdx.x;

    __shared__ float phi_s[NORB][NFEAT];
    __shared__ float W_s[NFEAT][NFEAT];
    __shared__ float tmp_s[NORB][NFEAT];
    __shared__ float G_s[NORB][NORB];
    __shared__ float ps_s[NORB];
    __shared__ int   x_s[NORB];
    __shared__ float Sv_s;
    __shared__ unsigned char m1_s[NCOL1];
    __shared__ double A1[NORB][NORB];
    __shared__ double A2[NORB][NORB];
    __shared__ double red_s[BLK / 64];
    __shared__ double det1_s, det2_s, inv1_s, inv2_s;

    // ---- stage inputs ----
    if (tid < NORB * NFEAT) phi_s[tid / NFEAT][tid % NFEAT] = mfv[(size_t)t * NORB * NFEAT + tid];
    if (tid < NFEAT * NFEAT) {
        int r = tid / NFEAT, c = tid % NFEAT;
        W_s[r][c] = w[r * NFEAT + c] + w[c * NFEAT + r];   // Wsym
    }
    if (tid < NORB) x_s[tid] = vn[t * NORB + tid];
    __syncthreads();

    // ---- psum, phi @ Wsym ----
    if (tid < NORB) {
        float s = 0.f;
        #pragma unroll
        for (int f = 0; f < NFEAT; ++f) s += phi_s[tid][f];
        ps_s[tid] = s;
    }
    if (tid < NORB * NFEAT) {
        int a = tid / NFEAT, f = tid % NFEAT;
        float s = 0.f;
        #pragma unroll
        for (int g = 0; g < NFEAT; ++g) s += phi_s[a][g] * W_s[g][f];
        tmp_s[a][f] = s;
    }
    __syncthreads();

    // ---- G = (phi @ Wsym) @ phi^T ;  S = psum . x ----
    if (tid < NORB * NORB) {
        int a = tid / NORB, i = tid % NORB;
        float s = 0.f;
        #pragma unroll
        for (int f = 0; f < NFEAT; ++f) s += tmp_s[a][f] * phi_s[i][f];
        G_s[a][i] = s;
    }
    if (tid == 0) {
        float s = 0.f;
        for (int a = 0; a < NORB; ++a) s += ps_s[a] * (float)x_s[a];
        Sv_s = s;
    }
    __syncthreads();

    // occupancy bitmask: bit a set iff x[a]==2
    int X2 = 0;
    #pragma unroll
    for (int a = 0; a < NORB; ++a) X2 |= (x_s[a] == 2) ? (1 << a) : 0;
    const float Sv = Sv_s;

    // ---- two-body: columns c = (((i*12+j)*12+p)*12+q) ----
    double acc = 0.0;
    const float* __restrict__ h2row = h2 + (size_t)t * NCOL2;
    for (int c = tid; c < NCOL2; c += BLK) {
        int q  = c % NORB;  int r1 = c / NORB;
        int p  = r1 % NORB; int r2 = r1 / NORB;
        int j  = r2 % NORB; int i  = r2 / NORB;
        int mn = 100, mx = -100;
        #pragma unroll
        for (int a = 0; a < NORB; ++a) {
            int v = 1 + ((X2 >> a) & 1)
                  + (int)(a == i) + (int)(a == q) - (int)(a == j) - (int)(a == p);
            mn = v < mn ? v : mn;
            mx = v > mx ? v : mx;
        }
        float h2v = h2row[c];
        float a2  = Sv + ps_s[i] + ps_s[q] - ps_s[j] - ps_s[p];
        if ((mx - mn == 1) && (h2v > 0.0f)) {
            double tm = (double)h2v * (double)a2;
            acc += tm * tm;
        }
    }
    double e2 = block_reduce_d(acc, red_s, tid);   // thread 0 only

    // ---- one-body mask + h1 sum ----
    double h1c = 0.0;
    if (tid < NCOL1) {
        int i = tid / NORB, j = tid % NORB;
        int mn = 100, mx = -100;
        #pragma unroll
        for (int a = 0; a < NORB; ++a) {
            int v = 1 + ((X2 >> a) & 1) + (int)(a == j) - (int)(a == i);
            mn = v < mn ? v : mn;
            mx = v > mx ? v : mx;
        }
        float h1v = h1[(size_t)t * NCOL1 + tid];
        bool m = (mx - mn == 1) && (h1v > 0.0f);
        m1_s[tid] = m ? 1 : 0;
        if (m) h1c = (double)h1v * (double)h1v;
    }
    __syncthreads();
    double h1sum = block_reduce_d(h1c, red_s, tid);  // thread 0 only

    // ---- S1 = s1f s1f^T (exact int), A1 = G .* S1, A2 = G ----
    if (tid < NCOL1) {
        int a = tid / NORB, b = tid % NORB;
        int xa = x_s[a], xb = x_s[b];
        int s = 0;
        for (int ii = 0; ii < NORB; ++ii) {
            #pragma unroll
            for (int jj = 0; jj < NORB; ++jj) {
                if (m1_s[ii * NORB + jj]) {
                    int va = xa + (int)(a == jj) - (int)(a == ii);
                    int vb = xb + (int)(b == jj) - (int)(b == ii);
                    s += va * vb;
                }
            }
        }
        A1[a][b] = (double)G_s[a][b] * (double)s;
        A2[a][b] = (double)G_s[a][b];
    }
    if (tid == 0) { det1_s = 1.0; det2_s = 1.0; }
    __syncthreads();

    // ---- two 12x12 LU factorizations (partial pivoting), run concurrently ----
    for (int k = 0; k < NORB; ++k) {
        if (tid == 0) {
            int pr = k; double mv = fabs(A1[k][k]);
            for (int r = k + 1; r < NORB; ++r) {
                double av = fabs(A1[r][k]);
                if (av > mv) { mv = av; pr = r; }
            }
            if (pr != k) {
                for (int c2 = k; c2 < NORB; ++c2) {
                    double tswap = A1[k][c2]; A1[k][c2] = A1[pr][c2]; A1[pr][c2] = tswap;
                }
                det1_s = -det1_s;
            }
            double piv = A1[k][k];
            det1_s *= piv;
            inv1_s = (piv != 0.0) ? 1.0 / piv : 0.0;
        }
        if (tid == 64) {
            int pr = k; double mv = fabs(A2[k][k]);
            for (int r = k + 1; r < NORB; ++r) {
                double av = fabs(A2[r][k]);
                if (av > mv) { mv = av; pr = r; }
            }
            if (pr != k) {
                for (int c2 = k; c2 < NORB; ++c2) {
                    double tswap = A2[k][c2]; A2[k][c2] = A2[pr][c2]; A2[pr][c2] = tswap;
                }
                det2_s = -det2_s;
            }
            double piv = A2[k][k];
            det2_s *= piv;
            inv2_s = (piv != 0.0) ? 1.0 / piv : 0.0;
        }
        __syncthreads();
        if (tid < NCOL1) {
            int i2 = tid / NORB, j2 = tid % NORB;
            if (i2 > k && j2 > k) A1[i2][j2] -= A1[i2][k] * inv1_s * A1[k][j2];
        }
        {
            int t2 = tid - 112;
            if (t2 >= 0 && t2 < NCOL1) {
                int i2 = t2 / NORB, j2 = t2 % NORB;
                if (i2 > k && j2 > k) A2[i2][j2] -= A2[i2][k] * inv2_s * A2[k][j2];
            }
        }
        __syncthreads();
    }

    if (tid == 0) {
        double e1 = det1_s * det1_s * h1sum;
        int n2 = __popc(X2);
        double prodx2 = (double)(1ull << (2 * n2));    // (prod x)^2 = 4^n2
        double pd = det2_s * prodx2;
        ep_ws[2 * t]     = e1 + e2;
        ep_ws[2 * t + 1] = pd * pd;
    }
}

extern "C" __global__ void eloc_final(const double* __restrict__ ep_ws,
                                      float* __restrict__ out, int B)
{
    int b = threadIdx.x;
    if (b < B) {
        double se = 0.0, sp = 0.0;
        for (int u = 0; u < 16; ++u) {
            double e = ep_ws[2 * (b * 16 + u)];
            double p = ep_ws[2 * (b * 16 + u) + 1];
            se += e * p;
            sp += p;
        }
        out[b] = (float)(se / sp);
    }
}

extern "C" void kernel_launch(void* const* d_in, const int* in_sizes, int n_in,
                              void* d_out, int out_size, void* d_ws, size_t ws_size,
                              hipStream_t stream) {
    const float* mfv = (const float*)d_in[0];
    const float* h1  = (const float*)d_in[1];
    const float* h2  = (const float*)d_in[2];
    const int*   vn  = (const int*)d_in[3];
    const float* w   = (const float*)d_in[4];
    float*  out = (float*)d_out;
    double* ep  = (double*)d_ws;

    const int T = in_sizes[0] / (NORB * NFEAT);   // 256
    const int B = T / 16;                          // 16

    hipLaunchKernelGGL(eloc_main, dim3(T), dim3(BLK), 0, stream,
                       mfv, h1, h2, vn, w, ep);
    hipLaunchKernelGGL(eloc_final, dim3(1), dim3(64), 0, stream, ep, out, B);
}

// Round 2
// 24.772 us; speedup vs baseline: 3.0332x; 3.0332x over previous
//
#include <hip/hip_runtime.h>

#define NORB   12
#define NFEAT  14
#define NCOL1  144
#define NCOL2  20736
#define NROWS  1728        // NORB^3 q-rows per sample
#define NSPLIT 9           // blocks per sample for two-body
#define RPB    192         // rows per two-body block (= block size)
#define BLKA   256

// Block-wide double reduction over 256 threads. Valid on thread 0 only.
__device__ inline double block_reduce_d(double v, double* red, int tid) {
    #pragma unroll
    for (int o = 32; o > 0; o >>= 1) v += __shfl_down(v, o, 64);
    if ((tid & 63) == 0) red[tid >> 6] = v;
    __syncthreads();
    double r = 0.0;
    if (tid == 0) {
        #pragma unroll
        for (int wv = 0; wv < BLKA / 64; ++wv) r += red[wv];
    }
    __syncthreads();
    return r;
}

// ---------------- Kernel A: per-sample prep + one-body + determinants ----------------
extern "C" __global__ void __launch_bounds__(BLKA)
eloc_prep(const float* __restrict__ mfv, const float* __restrict__ h1,
          const int* __restrict__ vn, const float* __restrict__ w,
          double* __restrict__ ep, float* __restrict__ prep)
{
    const int t   = blockIdx.x;
    const int tid = threadIdx.x;

    __shared__ float phi_s[NORB][NFEAT];
    __shared__ float W_s[NFEAT][NFEAT];
    __shared__ float tmp_s[NORB][NFEAT];
    __shared__ float G_s[NORB][NORB];
    __shared__ float ps_s[NORB];
    __shared__ int   x_s[NORB];
    __shared__ float Sv_s;
    __shared__ unsigned char m1_s[NCOL1];
    __shared__ int Ri_s[NORB], Rj_s[NORB], M_s;
    __shared__ double A1[NORB][NORB];
    __shared__ double A2[NORB][NORB];
    __shared__ double red_s[BLKA / 64];
    __shared__ double det_s[2];
    __shared__ double h1sum_s;

    // ---- stage ----
    if (tid < NORB * NFEAT) phi_s[tid / NFEAT][tid % NFEAT] = mfv[(size_t)t * NORB * NFEAT + tid];
    if (tid < NFEAT * NFEAT) {
        int r = tid / NFEAT, c = tid % NFEAT;
        W_s[r][c] = w[r * NFEAT + c] + w[c * NFEAT + r];
    }
    if (tid < NORB) x_s[tid] = vn[t * NORB + tid];
    __syncthreads();

    // ---- ps, phi @ Wsym ----
    if (tid < NORB) {
        float s = 0.f;
        #pragma unroll
        for (int f = 0; f < NFEAT; ++f) s += phi_s[tid][f];
        ps_s[tid] = s;
    }
    if (tid < NORB * NFEAT) {
        int a = tid / NFEAT, f = tid % NFEAT;
        float s = 0.f;
        #pragma unroll
        for (int g = 0; g < NFEAT; ++g) s += phi_s[a][g] * W_s[g][f];
        tmp_s[a][f] = s;
    }
    __syncthreads();

    if (tid < NCOL1) {
        int a = tid / NORB, i = tid % NORB;
        float s = 0.f;
        #pragma unroll
        for (int f = 0; f < NFEAT; ++f) s += tmp_s[a][f] * phi_s[i][f];
        G_s[a][i] = s;
    }
    if (tid == 0) {
        float s = 0.f;
        for (int a = 0; a < NORB; ++a) s += ps_s[a] * (float)x_s[a];
        Sv_s = s;
    }
    __syncthreads();

    int X2 = 0;
    #pragma unroll
    for (int a = 0; a < NORB; ++a) X2 |= (x_s[a] == 2) ? (1 << a) : 0;
    const int nx2 = ~X2 & 0xFFF;

    // ---- write per-sample prep struct for the two-body kernel ----
    if (tid < NORB)  prep[t * 16 + tid] = ps_s[tid];
    if (tid == NORB) prep[t * 16 + 12]  = Sv_s;
    if (tid == NORB + 1) prep[t * 16 + 13] = __int_as_float(X2);

    // ---- one-body mask (bit trick) + h1 sum ----
    double h1c = 0.0;
    if (tid < NCOL1) {
        int ii = tid / NORB, jj = tid % NORB;
        int um  = 0xFFF & ~((1 << ii) | (1 << jj));
        int hm1 = nx2 & um, hm2 = X2 & um;
        int mn = hm1 ? 1 : (hm2 ? 2 : 9);
        int mx = hm2 ? 2 : (hm1 ? 1 : -9);
        int d  = (ii == jj) ? 0 : 1;
        int vi = x_s[ii] - d, vj = x_s[jj] + d;
        mn = min(mn, min(vi, vj));
        mx = max(mx, max(vi, vj));
        float h1v = h1[(size_t)t * NCOL1 + tid];
        bool ok = (mx - mn == 1) && (h1v > 0.0f);
        m1_s[tid] = ok ? 1 : 0;
        if (ok) h1c = (double)h1v * (double)h1v;
    }
    __syncthreads();
    double h1sum = block_reduce_d(h1c, red_s, tid);
    if (tid == 0) h1sum_s = h1sum;

    // ---- row/col sums of the valid-pair matrix V (=m1) ----
    if (tid < NORB) {
        int ri = 0, rj = 0;
        #pragma unroll
        for (int o = 0; o < NORB; ++o) {
            ri += m1_s[tid * NORB + o];   // ii = tid
            rj += m1_s[o * NORB + tid];   // jj = tid
        }
        Ri_s[tid] = ri;
        Rj_s[tid] = rj;
    }
    __syncthreads();
    if (tid == 0) {
        int m = 0;
        #pragma unroll
        for (int o = 0; o < NORB; ++o) m += Ri_s[o];
        M_s = m;
    }
    __syncthreads();

    // ---- A1 = G .* S1 (analytic O(1) per entry), A2 = G ----
    if (tid < NCOL1) {
        int a = tid / NORB, b = tid % NORB;
        int xa = x_s[a], xb = x_s[b];
        int Da = Rj_s[a] - Ri_s[a], Db = Rj_s[b] - Ri_s[b];
        int s1 = xa * xb * M_s + xa * Db + xb * Da
               - (int)m1_s[b * NORB + a] - (int)m1_s[a * NORB + b];
        if (a == b) s1 += Rj_s[a] + Ri_s[a];
        A1[a][b] = (double)G_s[a][b] * (double)s1;
        A2[a][b] = (double)G_s[a][b];
    }
    __syncthreads();

    // ---- barrier-free in-register LU with partial pivoting; wave0: A1, wave1: A2 ----
    const int wv = tid >> 6, lane = tid & 63;
    if (wv < 2) {
        const double* Abase = (wv == 0) ? &A1[0][0] : &A2[0][0];
        const int rl = (lane < NORB) ? lane : 0;
        double a[NORB];
        #pragma unroll
        for (int c = 0; c < NORB; ++c) a[c] = Abase[rl * NORB + c];
        double det = 1.0;
        #pragma unroll
        for (int k = 0; k < NORB; ++k) {
            double key = (lane >= k && lane < NORB) ? fabs(a[k]) : -1.0;
            int idx = lane;
            #pragma unroll
            for (int off = 8; off >= 1; off >>= 1) {
                double k2 = __shfl_xor(key, off);
                int    i2 = __shfl_xor(idx, off);
                if (k2 > key || (k2 == key && i2 < idx)) { key = k2; idx = i2; }
            }
            int pr = idx;
            if (pr != k) det = -det;
            int src = (lane == k) ? pr : ((lane == pr) ? k : lane);
            #pragma unroll
            for (int c = 0; c < NORB; ++c) a[c] = __shfl(a[c], src);
            double pk[NORB];
            #pragma unroll
            for (int c = 0; c < NORB; ++c) pk[c] = __shfl(a[c], k);
            double piv = pk[k];
            det *= piv;
            double inv = (piv != 0.0) ? 1.0 / piv : 0.0;
            double f = (lane > k && lane < NORB) ? a[k] * inv : 0.0;
            #pragma unroll
            for (int c = 0; c < NORB; ++c) a[c] = fma(-f, pk[c], a[c]);
        }
        if (lane == 0) det_s[wv] = det;
    }
    __syncthreads();

    if (tid == 0) {
        double e1 = det_s[0] * det_s[0] * h1sum_s;
        int n2 = __popc(X2);
        double pd = det_s[1] * (double)(1ull << (2 * n2));
        ep[2 * t]     = e1;        // e2 added in the final kernel
        ep[2 * t + 1] = pd * pd;
    }
}

// ---------------- Kernel B: two-body partial sums ----------------
extern "C" __global__ void __launch_bounds__(RPB)
eloc_2body(const float* __restrict__ h2, const float* __restrict__ prep,
           double* __restrict__ part)
{
    const int tid = threadIdx.x;
    const int t   = blockIdx.x / NSPLIT;
    const int ch  = blockIdx.x % NSPLIT;

    __shared__ float ps_s[NORB];
    __shared__ double red_s[RPB / 64];

    if (tid < NORB) ps_s[tid] = prep[t * 16 + tid];
    __syncthreads();

    // uniform per-sample constants (block-uniform address -> scalar loads)
    const float4* pp = (const float4*)(prep + t * 16);
    const float4 u0 = pp[0], u1 = pp[1], u2 = pp[2], u3 = pp[3];
    const float Sv  = u3.x;
    const int   x2m = __float_as_int(u3.y);
    const int   nx2 = ~x2m & 0xFFF;

    const int r = ch * RPB + tid;                 // 0..1727
    const int i = r / 144, j = (r / NORB) % NORB, p = r % NORB;

    const float4* hr = (const float4*)(h2 + (size_t)t * NCOL2 + (size_t)r * NORB);
    const float4 ha = hr[0], hb = hr[1], hc = hr[2];

    const int bi = 1 << i, bj = 1 << j, bp = 1 << p;
    const int um0 = 0xFFF & ~(bi | bj | bp);
    const int xi = 1 + ((x2m >> i) & 1);
    const int xj = 1 + ((x2m >> j) & 1);
    const int xp = 1 + ((x2m >> p) & 1);
    const int basei = xi + 1 - ((bi >> j) & 1) - ((bi >> p) & 1);
    const int basej = xj + ((bj >> i) & 1) - 1 - ((bj >> p) & 1);
    const int basep = xp + ((bp >> i) & 1) - ((bp >> j) & 1) - 1;
    const float a2b = Sv + ps_s[i] - ps_s[j] - ps_s[p];

    float acc = 0.f;
#define COLQ(q, hv, psq) {                                                  \
        const int bq  = 1 << (q);                                           \
        const int um  = um0 & ~bq;                                          \
        const int hm1 = nx2 & um, hm2 = x2m & um;                           \
        int mn = hm1 ? 1 : (hm2 ? 2 : 9);                                   \
        int mx = hm2 ? 2 : (hm1 ? 1 : -9);                                  \
        const int iq = (bi >> (q)) & 1, jq = (bj >> (q)) & 1,               \
                  pq = (bp >> (q)) & 1;                                     \
        const int vi = basei + iq, vj = basej + jq, vp = basep + pq;        \
        const int xq = 1 + ((x2m >> (q)) & 1);                              \
        const int vq = xq + 1 + iq - jq - pq;                               \
        mn = min(min(mn, vi), min(vj, min(vp, vq)));                        \
        mx = max(max(mx, vi), max(vj, max(vp, vq)));                        \
        const bool ok = (mx - mn == 1) && ((hv) > 0.0f);                    \
        const float tq = ok ? (hv) * (a2b + (psq)) : 0.0f;                  \
        acc = fmaf(tq, tq, acc);                                            \
    }
    COLQ(0,  ha.x, u0.x)  COLQ(1,  ha.y, u0.y)  COLQ(2,  ha.z, u0.z)
    COLQ(3,  ha.w, u0.w)  COLQ(4,  hb.x, u1.x)  COLQ(5,  hb.y, u1.y)
    COLQ(6,  hb.z, u1.z)  COLQ(7,  hb.w, u1.w)  COLQ(8,  hc.x, u2.x)
    COLQ(9,  hc.y, u2.y)  COLQ(10, hc.z, u2.z)  COLQ(11, hc.w, u2.w)
#undef COLQ

    double accd = (double)acc;
    #pragma unroll
    for (int o = 32; o > 0; o >>= 1) accd += __shfl_down(accd, o, 64);
    const int lane = tid & 63, wv = tid >> 6;
    if (lane == 0) red_s[wv] = accd;
    __syncthreads();
    if (tid == 0) part[blockIdx.x] = red_s[0] + red_s[1] + red_s[2];
}

// ---------------- Kernel C: combine ----------------
extern "C" __global__ void __launch_bounds__(256)
eloc_final(const double* __restrict__ ep, const double* __restrict__ part,
           float* __restrict__ out, int T)
{
    const int s = threadIdx.x;
    __shared__ double se_s[256], sp_s[256];
    if (s < T) {
        double e2 = 0.0;
        #pragma unroll
        for (int k = 0; k < NSPLIT; ++k) e2 += part[s * NSPLIT + k];
        double e = ep[2 * s] + e2;
        double p = ep[2 * s + 1];
        se_s[s] = e * p;
        sp_s[s] = p;
    }
    __syncthreads();
    if (s < T / 16) {
        double se = 0.0, sp = 0.0;
        #pragma unroll
        for (int u = 0; u < 16; ++u) { se += se_s[s * 16 + u]; sp += sp_s[s * 16 + u]; }
        out[s] = (float)(se / sp);
    }
}

extern "C" void kernel_launch(void* const* d_in, const int* in_sizes, int n_in,
                              void* d_out, int out_size, void* d_ws, size_t ws_size,
                              hipStream_t stream) {
    const float* mfv = (const float*)d_in[0];
    const float* h1  = (const float*)d_in[1];
    const float* h2  = (const float*)d_in[2];
    const int*   vn  = (const int*)d_in[3];
    const float* w   = (const float*)d_in[4];
    float* out = (float*)d_out;

    const int T = in_sizes[0] / (NORB * NFEAT);   // 256

    double* ep   = (double*)d_ws;                 // 2T doubles
    double* part = ep + 2 * T;                    // NSPLIT*T doubles
    float*  prep = (float*)(part + NSPLIT * T);   // 16T floats

    hipLaunchKernelGGL(eloc_prep, dim3(T), dim3(BLKA), 0, stream,
                       mfv, h1, vn, w, ep, prep);
    hipLaunchKernelGGL(eloc_2body, dim3(T * NSPLIT), dim3(RPB), 0, stream,
                       h2, prep, part);
    hipLaunchKernelGGL(eloc_final, dim3(1), dim3(256), 0, stream, ep, part, out, T);
}